// Round 1
// baseline (2599.476 us; speedup 1.0000x reference)
//
#include <hip/hip_runtime.h>
#include <hip/hip_bf16.h>
#include <cstdint>
#include <cstddef>

#define B_   64
#define T_   196
#define D_   768
#define H_   12
#define HID_ 64
#define NT_  (B_ * T_)   // 12544

__device__ __forceinline__ float bf2f(uint16_t u) {
    uint32_t x = ((uint32_t)u) << 16;
    return __builtin_bit_cast(float, x);
}
__device__ __forceinline__ uint16_t f2bf(float f) {
    uint32_t x = __builtin_bit_cast(uint32_t, f);
    uint32_t r = (x + 0x7fffu + ((x >> 16) & 1u)) >> 16;
    return (uint16_t)r;
}

// ---------------------------------------------------------------------------
// K1: C_bf16[n][m] = sum_k A[n][k] * Bw[m][k] + bias[m]
//     A: [N][K] f32 row-major, Bw: [M][K] f32 row-major (NT gemm, K contiguous)
// grid: (N/64, M/64), block 256, 4x4 per thread
// ---------------------------------------------------------------------------
template<int KDIM>
__global__ __launch_bounds__(256)
void gemm_nt_bf16out(const float* __restrict__ A, const float* __restrict__ Bw,
                     const float* __restrict__ bias, uint16_t* __restrict__ C,
                     int Mtot)
{
    __shared__ float As[16][68];
    __shared__ float Bs[16][68];
    const int tid = threadIdx.x;
    const int n0 = blockIdx.x * 64, m0 = blockIdx.y * 64;
    const int lr = tid >> 2;          // 0..63
    const int lk = (tid & 3) << 2;    // 0,4,8,12
    const int tx = tid & 15, ty = tid >> 4;

    float acc[4][4];
#pragma unroll
    for (int i = 0; i < 4; i++)
#pragma unroll
        for (int jj = 0; jj < 4; jj++) acc[i][jj] = 0.f;

    const float* Ap = A + (size_t)(n0 + lr) * KDIM + lk;
    const float* Bp = Bw + (size_t)(m0 + lr) * KDIM + lk;

    for (int k0 = 0; k0 < KDIM; k0 += 16) {
        float4 av = *(const float4*)(Ap + k0);
        float4 bv = *(const float4*)(Bp + k0);
        As[lk + 0][lr] = av.x; As[lk + 1][lr] = av.y;
        As[lk + 2][lr] = av.z; As[lk + 3][lr] = av.w;
        Bs[lk + 0][lr] = bv.x; Bs[lk + 1][lr] = bv.y;
        Bs[lk + 2][lr] = bv.z; Bs[lk + 3][lr] = bv.w;
        __syncthreads();
#pragma unroll
        for (int k = 0; k < 16; k++) {
            float4 a = *(const float4*)&As[k][ty * 4];
            float4 b = *(const float4*)&Bs[k][tx * 4];
            float a4[4] = {a.x, a.y, a.z, a.w};
            float b4[4] = {b.x, b.y, b.z, b.w};
#pragma unroll
            for (int i = 0; i < 4; i++)
#pragma unroll
                for (int jj = 0; jj < 4; jj++) acc[i][jj] += a4[i] * b4[jj];
        }
        __syncthreads();
    }
#pragma unroll
    for (int i = 0; i < 4; i++) {
        const int n = n0 + ty * 4 + i;
#pragma unroll
        for (int jj = 0; jj < 4; jj++) {
            const int m = m0 + tx * 4 + jj;
            C[(size_t)n * Mtot + m] = f2bf(acc[i][jj] + bias[m]);
        }
    }
}

// ---------------------------------------------------------------------------
// K3: C_f32[n][m] = sum_k bf2f(A[n][k]) * Bw[m][k] + bias[m]
// ---------------------------------------------------------------------------
template<int KDIM>
__global__ __launch_bounds__(256)
void gemm_nt_bf16in_f32out(const uint16_t* __restrict__ A, const float* __restrict__ Bw,
                           const float* __restrict__ bias, float* __restrict__ C,
                           int Mtot)
{
    __shared__ float As[16][68];
    __shared__ float Bs[16][68];
    const int tid = threadIdx.x;
    const int n0 = blockIdx.x * 64, m0 = blockIdx.y * 64;
    const int lr = tid >> 2;
    const int lk = (tid & 3) << 2;
    const int tx = tid & 15, ty = tid >> 4;

    float acc[4][4];
#pragma unroll
    for (int i = 0; i < 4; i++)
#pragma unroll
        for (int jj = 0; jj < 4; jj++) acc[i][jj] = 0.f;

    const uint16_t* Ap = A + (size_t)(n0 + lr) * KDIM + lk;
    const float* Bp = Bw + (size_t)(m0 + lr) * KDIM + lk;

    for (int k0 = 0; k0 < KDIM; k0 += 16) {
        uint2 au = *(const uint2*)(Ap + k0);   // 4 bf16
        float4 bv = *(const float4*)(Bp + k0);
        As[lk + 0][lr] = bf2f((uint16_t)(au.x & 0xffffu));
        As[lk + 1][lr] = bf2f((uint16_t)(au.x >> 16));
        As[lk + 2][lr] = bf2f((uint16_t)(au.y & 0xffffu));
        As[lk + 3][lr] = bf2f((uint16_t)(au.y >> 16));
        Bs[lk + 0][lr] = bv.x; Bs[lk + 1][lr] = bv.y;
        Bs[lk + 2][lr] = bv.z; Bs[lk + 3][lr] = bv.w;
        __syncthreads();
#pragma unroll
        for (int k = 0; k < 16; k++) {
            float4 a = *(const float4*)&As[k][ty * 4];
            float4 b = *(const float4*)&Bs[k][tx * 4];
            float a4[4] = {a.x, a.y, a.z, a.w};
            float b4[4] = {b.x, b.y, b.z, b.w};
#pragma unroll
            for (int i = 0; i < 4; i++)
#pragma unroll
                for (int jj = 0; jj < 4; jj++) acc[i][jj] += a4[i] * b4[jj];
        }
        __syncthreads();
    }
#pragma unroll
    for (int i = 0; i < 4; i++) {
        const int n = n0 + ty * 4 + i;
#pragma unroll
        for (int jj = 0; jj < 4; jj++) {
            const int m = m0 + tx * 4 + jj;
            C[(size_t)n * Mtot + m] = acc[i][jj] + bias[m];
        }
    }
}

// ---------------------------------------------------------------------------
// K2: per-head bidirectional LSTM recurrence.
// grid = 24 chains (head,dir) x 8 batch-tiles of 8  = 192 blocks, 256 threads.
// Thread g owns gate row g (Wih/Whh rows in 128 VGPRs) for 8 batches.
// Cell update: thread (j = g&63, bq = g>>6) owns cells (bq, j) and (bq+4, j).
// ---------------------------------------------------------------------------
__global__ __launch_bounds__(256)
void lstm_rec(const uint16_t* __restrict__ xp,         // [NT][768] bf16
              const float* __restrict__ Wih_f, const float* __restrict__ Whh_f,
              const float* __restrict__ bih_f, const float* __restrict__ bhh_f,
              const float* __restrict__ Wih_r, const float* __restrict__ Whh_r,
              const float* __restrict__ bih_r, const float* __restrict__ bhh_r,
              uint16_t* __restrict__ y)                // [NT][1536] bf16
{
    const int blk   = blockIdx.x;
    const int btile = blk & 7;
    const int chain = blk >> 3;        // 0..23
    const int head  = chain % H_;
    const int dir   = chain / H_;
    const int b0    = btile * 8;
    const int g     = threadIdx.x;     // 0..255

    const float* Wih = dir ? Wih_r : Wih_f;
    const float* Whh = dir ? Whh_r : Whh_f;
    const float* bih = dir ? bih_r : bih_f;
    const float* bhh = dir ? bhh_r : bhh_f;

    __shared__ float xs[512];     // [8][64]
    __shared__ float hs[512];     // [8][64]
    __shared__ float Gs[2048];    // [8][256]

    float wi[64], wh[64];
    {
        const float* wip = Wih + ((size_t)head * 256 + g) * 64;
        const float* whp = Whh + ((size_t)head * 256 + g) * 64;
#pragma unroll
        for (int d = 0; d < 64; d += 4) {
            float4 a = *(const float4*)(wip + d);
            wi[d] = a.x; wi[d + 1] = a.y; wi[d + 2] = a.z; wi[d + 3] = a.w;
            float4 b = *(const float4*)(whp + d);
            wh[d] = b.x; wh[d + 1] = b.y; wh[d + 2] = b.z; wh[d + 3] = b.w;
        }
    }
    const float biasg = bih[head * 256 + g] + bhh[head * 256 + g];

    const int j  = g & 63;
    const int bq = g >> 6;
    float c0 = 0.f, c1 = 0.f;

    // init h = 0, prefetch x slice for t=0
    hs[g] = 0.f; hs[g + 256] = 0.f;
    {
        const int tt0 = dir ? (T_ - 1) : 0;
        const int idx = g * 2;
        const int bb = idx >> 6, dd = idx & 63;
        const uint16_t* xr = xp + ((size_t)(b0 + bb) * T_ + tt0) * D_ + head * 64 + dd;
        xs[idx] = bf2f(xr[0]); xs[idx + 1] = bf2f(xr[1]);
    }
    __syncthreads();

    for (int s = 0; s < T_; ++s) {
        const int tt = dir ? (T_ - 1 - s) : s;

        float acc[8];
#pragma unroll
        for (int b = 0; b < 8; b++) acc[b] = biasg;

#pragma unroll
        for (int d = 0; d < 64; d += 4) {
#pragma unroll
            for (int b = 0; b < 8; b++) {
                float4 xv = *(const float4*)&xs[b * 64 + d];
                acc[b] += xv.x * wi[d] + xv.y * wi[d + 1] + xv.z * wi[d + 2] + xv.w * wi[d + 3];
            }
        }
#pragma unroll
        for (int d = 0; d < 64; d += 4) {
#pragma unroll
            for (int b = 0; b < 8; b++) {
                float4 hv = *(const float4*)&hs[b * 64 + d];
                acc[b] += hv.x * wh[d] + hv.y * wh[d + 1] + hv.z * wh[d + 2] + hv.w * wh[d + 3];
            }
        }
#pragma unroll
        for (int b = 0; b < 8; b++) Gs[b * 256 + g] = acc[b];
        __syncthreads();   // G ready; everyone done reading xs/hs

#pragma unroll
        for (int half = 0; half < 2; ++half) {
            const int b = bq + half * 4;
            const float gi = Gs[b * 256 + j];
            const float gf = Gs[b * 256 + 64 + j];
            const float gg = Gs[b * 256 + 128 + j];
            const float go = Gs[b * 256 + 192 + j];
            const float i_ = 1.f / (1.f + __expf(-gi));
            const float f_ = 1.f / (1.f + __expf(-gf));
            const float g_ = 1.f - 2.f / (1.f + __expf(2.f * gg));
            const float o_ = 1.f / (1.f + __expf(-go));
            float& c = half ? c1 : c0;
            c = f_ * c + i_ * g_;
            const float h = o_ * (1.f - 2.f / (1.f + __expf(2.f * c)));
            hs[b * 64 + j] = h;
            y[((size_t)(b0 + b) * T_ + tt) * 1536 + dir * 768 + head * 64 + j] = f2bf(h);
        }
        if (s + 1 < T_) {
            const int tn = dir ? (T_ - 2 - s) : (s + 1);
            const int idx = g * 2;
            const int bb = idx >> 6, dd = idx & 63;
            const uint16_t* xr = xp + ((size_t)(b0 + bb) * T_ + tn) * D_ + head * 64 + dd;
            xs[idx] = bf2f(xr[0]); xs[idx + 1] = bf2f(xr[1]);
        }
        __syncthreads();   // hs / xs ready for next step
    }
}

// ---------------------------------------------------------------------------
extern "C" void kernel_launch(void* const* d_in, const int* in_sizes, int n_in,
                              void* d_out, int out_size, void* d_ws, size_t ws_size,
                              hipStream_t stream) {
    const float* x      = (const float*)d_in[0];
    const float* pre_W  = (const float*)d_in[1];
    const float* pre_b  = (const float*)d_in[2];
    const float* Wih_f  = (const float*)d_in[3];
    const float* Whh_f  = (const float*)d_in[4];
    const float* bih_f  = (const float*)d_in[5];
    const float* bhh_f  = (const float*)d_in[6];
    const float* Wih_r  = (const float*)d_in[7];
    const float* Whh_r  = (const float*)d_in[8];
    const float* bih_r  = (const float*)d_in[9];
    const float* bhh_r  = (const float*)d_in[10];
    const float* proj_W = (const float*)d_in[11];
    const float* proj_b = (const float*)d_in[12];
    float* out = (float*)d_out;

    uint16_t* xp = (uint16_t*)d_ws;                 // [NT][768]  bf16 (19.3 MB)
    uint16_t* y  = xp + (size_t)NT_ * D_;           // [NT][1536] bf16 (38.5 MB)

    dim3 g1(NT_ / 64, D_ / 64);
    gemm_nt_bf16out<768><<<g1, 256, 0, stream>>>(x, pre_W, pre_b, xp, D_);

    lstm_rec<<<192, 256, 0, stream>>>(xp, Wih_f, Whh_f, bih_f, bhh_f,
                                      Wih_r, Whh_r, bih_r, bhh_r, y);

    dim3 g3(NT_ / 64, D_ / 64);
    gemm_nt_bf16in_f32out<1536><<<g3, 256, 0, stream>>>(y, proj_W, proj_b, out, D_);
}